// Round 12
// baseline (402.042 us; speedup 1.0000x reference)
//
#include <hip/hip_runtime.h>

#define N 1024
#define NE 32768
#define S 4
#define STEPS 31
#define FEAT (S * STEPS)  // 124
#define PLANE ((size_t)S * N * N)   // 4 Mi elements (8 MB as ushort)
#define MAXT 192

typedef short short8 __attribute__((ext_vector_type(8)));
typedef short short4v __attribute__((ext_vector_type(4)));
typedef float f32x4 __attribute__((ext_vector_type(4)));

// ---- bf16 helpers (RNE) ---------------------------------------------------
__device__ __forceinline__ ushort f2bf(float x) {
    union { float f; unsigned u; } v; v.f = x;
    unsigned r = v.u + 0x7fffu + ((v.u >> 16) & 1u);
    return (ushort)(r >> 16);
}
__device__ __forceinline__ float bf2f(ushort h) {
    union { unsigned u; float f; } v; v.u = ((unsigned)h) << 16;
    return v.f;
}

__device__ __forceinline__ void gload16(const ushort* g, ushort* l) {
    __builtin_amdgcn_global_load_lds(
        (const __attribute__((address_space(1))) unsigned int*)g,
        (__attribute__((address_space(3))) unsigned int*)l, 16, 0, 0);
}

// ---------------------------------------------------------------------------
// Kernel: build P (split bf16 hi/lo), row-major [s][i][j].
// ---------------------------------------------------------------------------
__global__ __launch_bounds__(256) void build_P(const float* __restrict__ coords,
                                               const float* __restrict__ log_sigmas,
                                               ushort* __restrict__ Oh,
                                               ushort* __restrict__ Ol)
{
    const int i   = blockIdx.x;
    const int tid = threadIdx.x;

    float sg[S];
#pragma unroll
    for (int s = 0; s < S; ++s) sg[s] = expf(log_sigmas[s]);
#define CSWP(a, b) { float lo = fminf(sg[a], sg[b]); float hi = fmaxf(sg[a], sg[b]); sg[a] = lo; sg[b] = hi; }
    CSWP(0, 1) CSWP(2, 3) CSWP(0, 2) CSWP(1, 3) CSWP(1, 2)
#undef CSWP
    float inv2s2[S];
#pragma unroll
    for (int s = 0; s < S; ++s) inv2s2[s] = 1.0f / (2.0f * sg[s] * sg[s]);

    const float cx = coords[3 * i + 0];
    const float cy = coords[3 * i + 1];
    const float cz = coords[3 * i + 2];

    float w[4][S];
    float part[S] = {0.f, 0.f, 0.f, 0.f};
#pragma unroll
    for (int c = 0; c < 4; ++c) {
        const int j = tid + c * 256;
        const float dx = cx - coords[3 * j + 0];
        const float dy = cy - coords[3 * j + 1];
        const float dz = cz - coords[3 * j + 2];
        const float d2 = dx * dx + dy * dy + dz * dz;
#pragma unroll
        for (int s = 0; s < S; ++s) {
            const float v = (j == i) ? 0.0f : expf(-d2 * inv2s2[s]);
            w[c][s] = v;
            part[s] += v;
        }
    }

    __shared__ float red[S][256];
#pragma unroll
    for (int s = 0; s < S; ++s) red[s][tid] = part[s];
    __syncthreads();
    for (int st = 128; st > 0; st >>= 1) {
        if (tid < st) {
#pragma unroll
            for (int s = 0; s < S; ++s) red[s][tid] += red[s][tid + st];
        }
        __syncthreads();
    }

    float invden[S];
#pragma unroll
    for (int s = 0; s < S; ++s) invden[s] = 1.0f / fmaxf(red[s][0], 1e-12f);

#pragma unroll
    for (int c = 0; c < 4; ++c) {
        const int j = tid + c * 256;
#pragma unroll
        for (int s = 0; s < S; ++s) {
            const float p = w[c][s] * invden[s];
            const size_t off = ((size_t)s * N + i) * N + j;
            const ushort h = f2bf(p);
            Oh[off] = h;
            Ol[off] = f2bf(p - bf2f(h));
        }
    }
}

// ---------------------------------------------------------------------------
// Kernel: transpose hi/lo pair (used once, for BT1).
// ---------------------------------------------------------------------------
__global__ __launch_bounds__(256) void transpose_hl(const ushort* __restrict__ Xh,
                                                    const ushort* __restrict__ Xl,
                                                    ushort* __restrict__ Yh,
                                                    ushort* __restrict__ Yl)
{
    __shared__ float tile[64][65];
    const size_t zb = (size_t)blockIdx.z * N * N;
    const int tr = blockIdx.y * 64, tc = blockIdx.x * 64;
    const int tid = threadIdx.x;
    const int c  = tid & 63;
    const int r0 = tid >> 6;
#pragma unroll
    for (int i = 0; i < 16; ++i) {
        const int r = r0 + i * 4;
        const size_t idx = zb + (size_t)(tr + r) * N + tc + c;
        tile[r][c] = bf2f(Xh[idx]) + bf2f(Xl[idx]);
    }
    __syncthreads();
#pragma unroll
    for (int i = 0; i < 16; ++i) {
        const int r = r0 + i * 4;
        const size_t idx = zb + (size_t)(tc + r) * N + tr + c;
        const float x = tile[c][r];
        const ushort h = f2bf(x);
        Yh[idx] = h;
        if (Yl) Yl[idx] = f2bf(x - bf2f(h));
    }
}

// ---------------------------------------------------------------------------
// Kernel: bf16 MFMA GEMM, 128x128 tile, BK=32, 8 waves, 32x64 wave slice
// (proven round-10).  Quad-buffered LDS, depth-2 counted-vmcnt prefetch, one
// barrier per K-step.  s_setprio(1) around the MFMA cluster.
// SPLIT=1: C = (Ah+Al)@B, B=(BTh+BTl)^T, 3 MFMA passes, split output + CTh.
// SPLIT=0: C = Ah@BTh^T, 1 pass, hi-only output.
// ---------------------------------------------------------------------------
template <bool SPLIT>
__global__ __launch_bounds__(512) void gemm_tile(const ushort* __restrict__ Ah,
                                                 const ushort* __restrict__ Al,
                                                 const ushort* __restrict__ BTh,
                                                 const ushort* __restrict__ BTl,
                                                 ushort* __restrict__ Ch,
                                                 ushort* __restrict__ Cl,
                                                 ushort* __restrict__ CTh)
{
    constexpr int NP = SPLIT ? 4 : 2;           // LDS parts
    __shared__ ushort smem[4][NP][128 * 32];    // 128 KB (split) / 64 KB
    const int tid  = threadIdx.x;
    const int w    = tid >> 6;                  // wave 0..7
    const int lane = tid & 63;
    const int wr   = w >> 1;                    // wave row-block 0..3
    const int wc   = w & 1;                     // wave col-block 0..1
    const size_t zb = (size_t)blockIdx.z * N * N;
    const int tr = blockIdx.y * 128;
    const int tc = blockIdx.x * 128;

    const ushort* gA0 = Ah  + zb + (size_t)tr * N;
    const ushort* gA1 = SPLIT ? (Al  + zb + (size_t)tr * N) : nullptr;
    const ushort* gB0 = BTh + zb + (size_t)tc * N;
    const ushort* gB1 = SPLIT ? (BTl + zb + (size_t)tc * N) : nullptr;

    f32x4 acc[2][4] = {};                       // wave's 32x64 slice

    auto STAGE = [&](int bufi, int k0) __attribute__((always_inline)) {
        const int row = tid >> 2;               // 0..127
        const int kg  = (tid & 3) ^ ((row >> 1) & 3);
        const size_t go = (size_t)row * N + k0 + kg * 8;
        const int lb = w * 512;                 // wave-uniform LDS base (elems)
        gload16(gA0 + go, &smem[bufi][0][lb]);
        if constexpr (SPLIT) {
            gload16(gA1 + go, &smem[bufi][1][lb]);
            gload16(gB0 + go, &smem[bufi][2][lb]);
            gload16(gB1 + go, &smem[bufi][3][lb]);
        } else {
            gload16(gB0 + go, &smem[bufi][1][lb]);
        }
    };

    const int lrow = lane & 15;
    const int lkg  = lane >> 4;

    auto COMPUTE = [&](int bufi) __attribute__((always_inline)) {
        short8 ah[2], al[2], bh[4], bl[4];
#pragma unroll
        for (int m = 0; m < 2; ++m) {
            const int arow = wr * 32 + m * 16 + lrow;
            const int aoff = arow * 32 + ((lkg ^ ((arow >> 1) & 3)) << 3);
            ah[m] = *(const short8*)&smem[bufi][0][aoff];
            if constexpr (SPLIT) al[m] = *(const short8*)&smem[bufi][1][aoff];
        }
#pragma unroll
        for (int n = 0; n < 4; ++n) {
            const int brow = wc * 64 + n * 16 + lrow;
            const int boff = brow * 32 + ((lkg ^ ((brow >> 1) & 3)) << 3);
            if constexpr (SPLIT) {
                bh[n] = *(const short8*)&smem[bufi][2][boff];
                bl[n] = *(const short8*)&smem[bufi][3][boff];
            } else {
                bh[n] = *(const short8*)&smem[bufi][1][boff];
            }
        }
        __builtin_amdgcn_s_setprio(1);
#pragma unroll
        for (int m = 0; m < 2; ++m)
#pragma unroll
            for (int n = 0; n < 4; ++n) {
                acc[m][n] = __builtin_amdgcn_mfma_f32_16x16x32_bf16(ah[m], bh[n], acc[m][n], 0, 0, 0);
                if constexpr (SPLIT) {
                    acc[m][n] = __builtin_amdgcn_mfma_f32_16x16x32_bf16(ah[m], bl[n], acc[m][n], 0, 0, 0);
                    acc[m][n] = __builtin_amdgcn_mfma_f32_16x16x32_bf16(al[m], bh[n], acc[m][n], 0, 0, 0);
                }
            }
        __builtin_amdgcn_s_setprio(0);
    };

    STAGE(0, 0);
    STAGE(1, 32);
#pragma unroll 1
    for (int t = 0; t < 32; ++t) {
        __builtin_amdgcn_sched_barrier(0);
        if (t < 30) {
            STAGE((t + 2) & 3, (t + 2) * 32);
            if constexpr (SPLIT) asm volatile("s_waitcnt vmcnt(8)" ::: "memory");
            else                 asm volatile("s_waitcnt vmcnt(4)" ::: "memory");
        } else if (t == 30) {
            if constexpr (SPLIT) asm volatile("s_waitcnt vmcnt(4)" ::: "memory");
            else                 asm volatile("s_waitcnt vmcnt(2)" ::: "memory");
        } else {
            asm volatile("s_waitcnt vmcnt(0)" ::: "memory");
        }
        __builtin_amdgcn_s_barrier();                 // tile t visible to all
        __builtin_amdgcn_sched_barrier(0);
        COMPUTE(t & 3);
        __builtin_amdgcn_sched_barrier(0);
    }

    // epilogue
#pragma unroll
    for (int m = 0; m < 2; ++m)
#pragma unroll
    for (int n = 0; n < 4; ++n) {
        const f32x4 v = acc[m][n];
        ushort hs[4], ls[4];
#pragma unroll
        for (int r = 0; r < 4; ++r) {
            const float x = v[r];
            hs[r] = f2bf(x);
            ls[r] = f2bf(x - bf2f(hs[r]));
        }
        const int row0 = tr + wr * 32 + m * 16 + lkg * 4;
        const int col  = tc + wc * 64 + n * 16 + lrow;
#pragma unroll
        for (int r = 0; r < 4; ++r) {
            const size_t idx = zb + (size_t)(row0 + r) * N + col;
            Ch[idx] = hs[r];
            if constexpr (SPLIT) Cl[idx] = ls[r];
        }
        if constexpr (SPLIT) {
            if (CTh) {
                short4v hv;
                hv[0] = (short)hs[0]; hv[1] = (short)hs[1];
                hv[2] = (short)hs[2]; hv[3] = (short)hs[3];
                *(short4v*)&CTh[zb + (size_t)col * N + row0] = hv;
            }
        }
    }
}

// ---------------------------------------------------------------------------
// Kernel: gather diag + edges (fallback path only).
// ---------------------------------------------------------------------------
__global__ __launch_bounds__(256) void gather_hl(const ushort* __restrict__ Ph,
                                                 const ushort* __restrict__ Pl,
                                                 const int* __restrict__ eidx,
                                                 float* __restrict__ out,
                                                 int t)
{
    const int tid = blockIdx.x * blockDim.x + threadIdx.x;
    const int ND = S * N;
    if (tid < ND) {
        const int s = tid >> 10;
        const int n = tid & (N - 1);
        const size_t off = ((size_t)s * N + n) * N + n;
        float v = bf2f(Ph[off]);
        if (Pl) v += bf2f(Pl[off]);
        out[(size_t)n * FEAT + s * STEPS + t] = v;
    } else {
        const int idx = tid - ND;
        if (idx >= S * NE) return;
        const int s = idx >> 15;
        const int e = idx & (NE - 1);
        const int i = eidx[e];
        const int j = eidx[NE + e];
        const size_t off = ((size_t)s * N + i) * N + j;
        float v = bf2f(Ph[off]);
        if (Pl) v += bf2f(Pl[off]);
        out[(size_t)N * FEAT + (size_t)e * FEAT + s * STEPS + t] = v;
    }
}

// ---------------------------------------------------------------------------
// Bucketing (counting sort of edges by destination column j = eidx[NE+e]).
// ---------------------------------------------------------------------------
__global__ __launch_bounds__(256) void zero_aux(int* __restrict__ p, int n)
{
    for (int i = blockIdx.x * 256 + threadIdx.x; i < n; i += gridDim.x * 256) p[i] = 0;
}

__global__ __launch_bounds__(256) void edge_hist(const int* __restrict__ eidx,
                                                 int* __restrict__ hist)
{
    const int e = blockIdx.x * 256 + threadIdx.x;
    if (e < NE) atomicAdd(&hist[eidx[NE + e]], 1);
}

__global__ __launch_bounds__(1024) void scan1024(const int* __restrict__ hist,
                                                 int* __restrict__ offs)
{
    __shared__ int tmp[1024];
    const int t = threadIdx.x;
    tmp[t] = hist[t];
    __syncthreads();
    for (int d = 1; d < 1024; d <<= 1) {
        int v = (t >= d) ? tmp[t - d] : 0;
        __syncthreads();
        tmp[t] += v;
        __syncthreads();
    }
    offs[t + 1] = tmp[t];
    if (t == 0) offs[0] = 0;
}

__global__ __launch_bounds__(256) void edge_scatter(const int* __restrict__ eidx,
                                                    const int* __restrict__ offs,
                                                    int* __restrict__ cursor,
                                                    int* __restrict__ perm)
{
    const int e = blockIdx.x * 256 + threadIdx.x;
    if (e < NE) {
        const int j = eidx[NE + e];
        const int pos = atomicAdd(&cursor[j], 1);
        perm[offs[j] + pos] = e;
    }
}

// ---------------------------------------------------------------------------
// Kernel: full-feature extraction, K-SPLIT across two dispatches so each
// phase's per-XCD A-gather working set (3 planes x 1024 rows x 1KB half-row
// = 3 MB) fits the 4 MB private L2 (the single-pass 6 MB footprint thrashed
// to L3 — 114 us invariant across 6 structural variants).
//   PHASE 0: cols [0,512).  Stages full BT rows (direct k=1..8 needs
//            arbitrary-column reads), writes out with '='.
//   PHASE 1: cols [512,1024).  Stages upper half-rows only, out '+='.
// Work item = (column j, sigma s) via XCD pair-swizzle (bijective).
// LDS B operand rows 0..6 = BT_{b=1..7}[j,:], row 7 = BT8[j,:].
// C layout: col=lane&15 (=b), row=(lane>>4)*4+r (=task) [m89-verified].
// ---------------------------------------------------------------------------
template <int PHASE>
__global__ __launch_bounds__(256) void extract_k(const ushort* __restrict__ BTe,  // 7 planes
                                                 const ushort* __restrict__ BT8,
                                                 const ushort* __restrict__ A8,
                                                 const ushort* __restrict__ A16,
                                                 const ushort* __restrict__ A24,
                                                 const int* __restrict__ eidx,
                                                 const int* __restrict__ perm,
                                                 const int* __restrict__ offs,
                                                 float* __restrict__ out)
{
    const int id = blockIdx.x;
    const int s  = (id & 7) >> 1;
    const int j  = (id >> 3) * 2 + (id & 1);
    const int tid  = threadIdx.x;
    const int wave = tid >> 6;
    const int lane = tid & 63;

    constexpr int BTW = (PHASE == 0) ? 1032 : 520;   // staged row width (elems)
    constexpr int KOFF = (PHASE == 0) ? 0 : 512;     // global column offset
    __shared__ __align__(16) ushort bt[8][BTW];
    __shared__ int tlist[MAXT];
    __shared__ int elist[MAXT];

    const int base  = offs[j];
    const int cnt   = min(offs[j + 1] - base, MAXT - 1);
    const int ntask = cnt + 1;                   // + diag task
    const int ngrp  = (ntask + 15) >> 4;

    for (int t0 = tid; t0 < MAXT; t0 += 256) {
        int e = -2, i = j;
        if (t0 < cnt)       { e = perm[base + t0]; i = eidx[e]; }
        else if (t0 == cnt) { e = -1; }
        tlist[t0] = i;
        elist[t0] = e;
    }

    constexpr int NCH = (PHASE == 0) ? 128 : 64;     // 8-elem chunks per row
    for (int c = tid; c < 8 * NCH; c += 256) {
        const int b  = c / NCH;
        const int ch = c % NCH;
        const size_t rowoff = ((size_t)s * N + j) * N + KOFF + ch * 8;
        const short8 v = (b < 7)
            ? *(const short8*)&BTe[(size_t)b * PLANE + rowoff]
            : *(const short8*)&BT8[rowoff];
        *(short8*)&bt[b][ch * 8] = v;
    }
    __syncthreads();

    // ---- k = 1..8 straight from LDS (phase 0 only; full rows staged) ----
    if constexpr (PHASE == 0) {
        for (int t0 = tid; t0 < ntask; t0 += 256) {
            const int i = tlist[t0];
            const int e = elist[t0];
            const size_t obase = (e >= 0)
                ? ((size_t)N * FEAT + (size_t)e * FEAT + (size_t)s * STEPS)
                : ((size_t)j * FEAT + (size_t)s * STEPS);
#pragma unroll
            for (int b = 0; b < 8; ++b)
                out[obase + b] = bf2f(bt[b][i]);
        }
    }

    // ---- k = 9..31 via MFMA over this phase's K-half ----
    const int nidx = lane & 15;
    const int koff = (lane >> 4) * 8;
    const ushort* bt_ptr = &bt[nidx < 7 ? nidx : 7][koff];

    for (int g = wave; g < ngrp; g += 4) {
        const int i = tlist[g * 16 + nidx];
        const size_t abase = ((size_t)s * N + i) * N + KOFF + koff;
        const ushort* pa0 = A8  + abase;
        const ushort* pa1 = A16 + abase;
        const ushort* pa2 = A24 + abase;

        f32x4 acc0 = {}, acc1 = {}, acc2 = {};
#pragma unroll 4
        for (int ks = 0; ks < 16; ++ks) {
            const short8 bf  = *(const short8*)(bt_ptr + ks * 32);
            const short8 af0 = *(const short8*)(pa0 + ks * 32);
            const short8 af1 = *(const short8*)(pa1 + ks * 32);
            const short8 af2 = *(const short8*)(pa2 + ks * 32);
            acc0 = __builtin_amdgcn_mfma_f32_16x16x32_bf16(af0, bf, acc0, 0, 0, 0);
            acc1 = __builtin_amdgcn_mfma_f32_16x16x32_bf16(af1, bf, acc1, 0, 0, 0);
            acc2 = __builtin_amdgcn_mfma_f32_16x16x32_bf16(af2, bf, acc2, 0, 0, 0);
        }

        if (nidx < 8) {
            const int m0 = (lane >> 4) * 4;
#pragma unroll
            for (int r = 0; r < 4; ++r) {
                const int e = elist[g * 16 + m0 + r];
                if (e >= -1) {
                    const size_t obase = (e >= 0)
                        ? ((size_t)N * FEAT + (size_t)e * FEAT + (size_t)s * STEPS)
                        : ((size_t)j * FEAT + (size_t)s * STEPS);
                    if constexpr (PHASE == 0) {
                        out[obase + 8  + nidx] = acc0[r];          // k = 9..16
                        out[obase + 16 + nidx] = acc1[r];          // k = 17..24
                        if (nidx < 7)
                            out[obase + 24 + nidx] = acc2[r];      // k = 25..31
                    } else {
                        out[obase + 8  + nidx] += acc0[r];
                        out[obase + 16 + nidx] += acc1[r];
                        if (nidx < 7)
                            out[obase + 24 + nidx] += acc2[r];
                    }
                }
            }
        }
    }
}

// ---------------------------------------------------------------------------
extern "C" void kernel_launch(void* const* d_in, const int* in_sizes, int n_in,
                              void* d_out, int out_size, void* d_ws, size_t ws_size,
                              hipStream_t stream)
{
    const float* coords     = (const float*)d_in[0];
    const float* log_sigmas = (const float*)d_in[1];
    const int*   eidx       = (const int*)d_in[2];
    float*       out        = (float*)d_out;

    ushort* W = (ushort*)d_ws;
    const dim3 ggrid(N / 128, N / 128, S);
    const dim3 tgrid(16, 16, S);

    const size_t AUX_INTS = 1024 + 1024 + 1025 + NE;
    const size_t NEED_A   = 15 * PLANE * sizeof(ushort) + AUX_INTS * sizeof(int);

    if (ws_size >= NEED_A) {
        ushort* A0h = W + 0 * PLANE;  ushort* A0l = W + 1 * PLANE;
        ushort* A1h = W + 2 * PLANE;  ushort* A1l = W + 3 * PLANE;
        ushort* A2h = W + 4 * PLANE;
        ushort* BT1l = W + 5 * PLANE;
        ushort* BT8h = W + 6 * PLANE;           // plane 7 unused
        ushort* BTe  = W + 8 * PLANE;           // 7 planes, b=1..7
        int* hist   = (int*)(W + 15 * PLANE);
        int* cursor = hist + 1024;
        int* offs   = cursor + 1024;
        int* perm   = offs + 1025;

        zero_aux<<<8, 256, 0, stream>>>(hist, 2048);   // hist + cursor (contiguous)
        edge_hist<<<NE / 256, 256, 0, stream>>>(eidx, hist);
        scan1024<<<1, 1024, 0, stream>>>(hist, offs);
        edge_scatter<<<NE / 256, 256, 0, stream>>>(eidx, offs, cursor, perm);

        build_P<<<N, 256, 0, stream>>>(coords, log_sigmas, A0h, A0l);
        transpose_hl<<<tgrid, 256, 0, stream>>>(A0h, A0l, BTe + 0 * PLANE, BT1l);

        // chain P^2..P^8 (split), CT fused into BTe[1..6] / BT8h
        ushort* cur_h = A0h; ushort* cur_l = A0l;
        ushort* nxt_h = A1h; ushort* nxt_l = A1l;
        for (int m = 2; m <= 8; ++m) {
            ushort* cth = (m < 8) ? BTe + (size_t)(m - 1) * PLANE : BT8h;
            gemm_tile<true><<<ggrid, 512, 0, stream>>>(cur_h, cur_l, BTe, BT1l,
                                                       nxt_h, nxt_l, cth);
            ushort* th = cur_h; ushort* tl = cur_l;
            cur_h = nxt_h; cur_l = nxt_l; nxt_h = th; nxt_l = tl;
        }
        // cur = P^8 (h,l); nxt planes free
        ushort* P8h  = cur_h;
        ushort* P16h = nxt_h;
        gemm_tile<false><<<ggrid, 512, 0, stream>>>(P8h, (ushort*)nullptr,
                                                    BT8h, (ushort*)nullptr,
                                                    P16h, (ushort*)nullptr, (ushort*)nullptr);
        gemm_tile<false><<<ggrid, 512, 0, stream>>>(P16h, (ushort*)nullptr,
                                                    BT8h, (ushort*)nullptr,
                                                    A2h, (ushort*)nullptr, (ushort*)nullptr);

        extract_k<0><<<N * S, 256, 0, stream>>>(BTe, BT8h, P8h, P16h, A2h,
                                                eidx, perm, offs, out);
        extract_k<1><<<N * S, 256, 0, stream>>>(BTe, BT8h, P8h, P16h, A2h,
                                                eidx, perm, offs, out);
    } else {
        // ---- fallback: linear chain (6 planes = 48 MB) ----
        ushort* ping_h = W + 0 * PLANE; ushort* ping_l = W + 1 * PLANE;
        ushort* pong_h = W + 2 * PLANE; ushort* pong_l = W + 3 * PLANE;
        ushort* bt_h   = W + 4 * PLANE; ushort* bt_l   = W + 5 * PLANE;
        const int gather_blocks = (S * N + S * NE + 255) / 256;

        build_P<<<N, 256, 0, stream>>>(coords, log_sigmas, ping_h, ping_l);
        gather_hl<<<gather_blocks, 256, 0, stream>>>(ping_h, ping_l, eidx, out, 0);
        transpose_hl<<<tgrid, 256, 0, stream>>>(ping_h, ping_l, bt_h, bt_l);

        ushort* cur_h = ping_h; ushort* cur_l = ping_l;
        ushort* nxt_h = pong_h; ushort* nxt_l = pong_l;
        for (int k = 2; k <= STEPS; ++k) {
            gemm_tile<true><<<ggrid, 512, 0, stream>>>(cur_h, cur_l, bt_h, bt_l,
                                                       nxt_h, nxt_l, (ushort*)nullptr);
            gather_hl<<<gather_blocks, 256, 0, stream>>>(nxt_h, nxt_l, eidx, out, k - 1);
            ushort* th = cur_h; ushort* tl = cur_l;
            cur_h = nxt_h; cur_l = nxt_l; nxt_h = th; nxt_l = tl;
        }
    }
}

// Round 13
// 353.661 us; speedup vs baseline: 1.1368x; 1.1368x over previous
//
#include <hip/hip_runtime.h>

#define N 1024
#define NE 32768
#define S 4
#define STEPS 31
#define FEAT (S * STEPS)  // 124
#define PLANE ((size_t)S * N * N)   // 4 Mi elements (8 MB as ushort)
#define MAXT 192

typedef short short8 __attribute__((ext_vector_type(8)));
typedef short short4v __attribute__((ext_vector_type(4)));
typedef float f32x4 __attribute__((ext_vector_type(4)));

// ---- bf16 helpers (RNE) ---------------------------------------------------
__device__ __forceinline__ ushort f2bf(float x) {
    union { float f; unsigned u; } v; v.f = x;
    unsigned r = v.u + 0x7fffu + ((v.u >> 16) & 1u);
    return (ushort)(r >> 16);
}
__device__ __forceinline__ float bf2f(ushort h) {
    union { unsigned u; float f; } v; v.u = ((unsigned)h) << 16;
    return v.f;
}

__device__ __forceinline__ void gload16(const ushort* g, ushort* l) {
    __builtin_amdgcn_global_load_lds(
        (const __attribute__((address_space(1))) unsigned int*)g,
        (__attribute__((address_space(3))) unsigned int*)l, 16, 0, 0);
}

// ---------------------------------------------------------------------------
// Kernel: build P (split bf16 hi/lo), row-major [s][i][j].
// ---------------------------------------------------------------------------
__global__ __launch_bounds__(256) void build_P(const float* __restrict__ coords,
                                               const float* __restrict__ log_sigmas,
                                               ushort* __restrict__ Oh,
                                               ushort* __restrict__ Ol)
{
    const int i   = blockIdx.x;
    const int tid = threadIdx.x;

    float sg[S];
#pragma unroll
    for (int s = 0; s < S; ++s) sg[s] = expf(log_sigmas[s]);
#define CSWP(a, b) { float lo = fminf(sg[a], sg[b]); float hi = fmaxf(sg[a], sg[b]); sg[a] = lo; sg[b] = hi; }
    CSWP(0, 1) CSWP(2, 3) CSWP(0, 2) CSWP(1, 3) CSWP(1, 2)
#undef CSWP
    float inv2s2[S];
#pragma unroll
    for (int s = 0; s < S; ++s) inv2s2[s] = 1.0f / (2.0f * sg[s] * sg[s]);

    const float cx = coords[3 * i + 0];
    const float cy = coords[3 * i + 1];
    const float cz = coords[3 * i + 2];

    float w[4][S];
    float part[S] = {0.f, 0.f, 0.f, 0.f};
#pragma unroll
    for (int c = 0; c < 4; ++c) {
        const int j = tid + c * 256;
        const float dx = cx - coords[3 * j + 0];
        const float dy = cy - coords[3 * j + 1];
        const float dz = cz - coords[3 * j + 2];
        const float d2 = dx * dx + dy * dy + dz * dz;
#pragma unroll
        for (int s = 0; s < S; ++s) {
            const float v = (j == i) ? 0.0f : expf(-d2 * inv2s2[s]);
            w[c][s] = v;
            part[s] += v;
        }
    }

    __shared__ float red[S][256];
#pragma unroll
    for (int s = 0; s < S; ++s) red[s][tid] = part[s];
    __syncthreads();
    for (int st = 128; st > 0; st >>= 1) {
        if (tid < st) {
#pragma unroll
            for (int s = 0; s < S; ++s) red[s][tid] += red[s][tid + st];
        }
        __syncthreads();
    }

    float invden[S];
#pragma unroll
    for (int s = 0; s < S; ++s) invden[s] = 1.0f / fmaxf(red[s][0], 1e-12f);

#pragma unroll
    for (int c = 0; c < 4; ++c) {
        const int j = tid + c * 256;
#pragma unroll
        for (int s = 0; s < S; ++s) {
            const float p = w[c][s] * invden[s];
            const size_t off = ((size_t)s * N + i) * N + j;
            const ushort h = f2bf(p);
            Oh[off] = h;
            Ol[off] = f2bf(p - bf2f(h));
        }
    }
}

// ---------------------------------------------------------------------------
// Kernel: transpose hi/lo pair (used once, for BT1).
// ---------------------------------------------------------------------------
__global__ __launch_bounds__(256) void transpose_hl(const ushort* __restrict__ Xh,
                                                    const ushort* __restrict__ Xl,
                                                    ushort* __restrict__ Yh,
                                                    ushort* __restrict__ Yl)
{
    __shared__ float tile[64][65];
    const size_t zb = (size_t)blockIdx.z * N * N;
    const int tr = blockIdx.y * 64, tc = blockIdx.x * 64;
    const int tid = threadIdx.x;
    const int c  = tid & 63;
    const int r0 = tid >> 6;
#pragma unroll
    for (int i = 0; i < 16; ++i) {
        const int r = r0 + i * 4;
        const size_t idx = zb + (size_t)(tr + r) * N + tc + c;
        tile[r][c] = bf2f(Xh[idx]) + bf2f(Xl[idx]);
    }
    __syncthreads();
#pragma unroll
    for (int i = 0; i < 16; ++i) {
        const int r = r0 + i * 4;
        const size_t idx = zb + (size_t)(tc + r) * N + tr + c;
        const float x = tile[c][r];
        const ushort h = f2bf(x);
        Yh[idx] = h;
        if (Yl) Yl[idx] = f2bf(x - bf2f(h));
    }
}

// ---------------------------------------------------------------------------
// Kernel: bf16 MFMA GEMM, 128x128 tile, BK=32, 8 waves, 32x64 wave slice,
// quad-buffered LDS, depth-2 counted-vmcnt prefetch, one barrier per K-step,
// setprio around the MFMA cluster (proven round-10/11 schedule).
// SPLIT=1: C = (Ah+Al)@B, B=(BTh+BTl)^T, 3 MFMA passes.
// SPLIT=0: C = Ah@BTh^T, 1 pass.
// Outputs all nullable: Ch/Cl row-major hi/lo; CTh/CTl transposed hi/lo.
// (Leaf powers write CT only; chain powers write C + CT.)
// ---------------------------------------------------------------------------
template <bool SPLIT>
__global__ __launch_bounds__(512) void gemm_tile(const ushort* __restrict__ Ah,
                                                 const ushort* __restrict__ Al,
                                                 const ushort* __restrict__ BTh,
                                                 const ushort* __restrict__ BTl,
                                                 ushort* __restrict__ Ch,
                                                 ushort* __restrict__ Cl,
                                                 ushort* __restrict__ CTh,
                                                 ushort* __restrict__ CTl)
{
    constexpr int NP = SPLIT ? 4 : 2;           // LDS parts
    __shared__ ushort smem[4][NP][128 * 32];    // 128 KB (split) / 64 KB
    const int tid  = threadIdx.x;
    const int w    = tid >> 6;                  // wave 0..7
    const int lane = tid & 63;
    const int wr   = w >> 1;                    // wave row-block 0..3
    const int wc   = w & 1;                     // wave col-block 0..1
    const size_t zb = (size_t)blockIdx.z * N * N;
    const int tr = blockIdx.y * 128;
    const int tc = blockIdx.x * 128;

    const ushort* gA0 = Ah  + zb + (size_t)tr * N;
    const ushort* gA1 = SPLIT ? (Al  + zb + (size_t)tr * N) : nullptr;
    const ushort* gB0 = BTh + zb + (size_t)tc * N;
    const ushort* gB1 = SPLIT ? (BTl + zb + (size_t)tc * N) : nullptr;

    f32x4 acc[2][4] = {};                       // wave's 32x64 slice

    auto STAGE = [&](int bufi, int k0) __attribute__((always_inline)) {
        const int row = tid >> 2;               // 0..127
        const int kg  = (tid & 3) ^ ((row >> 1) & 3);
        const size_t go = (size_t)row * N + k0 + kg * 8;
        const int lb = w * 512;                 // wave-uniform LDS base (elems)
        gload16(gA0 + go, &smem[bufi][0][lb]);
        if constexpr (SPLIT) {
            gload16(gA1 + go, &smem[bufi][1][lb]);
            gload16(gB0 + go, &smem[bufi][2][lb]);
            gload16(gB1 + go, &smem[bufi][3][lb]);
        } else {
            gload16(gB0 + go, &smem[bufi][1][lb]);
        }
    };

    const int lrow = lane & 15;
    const int lkg  = lane >> 4;

    auto COMPUTE = [&](int bufi) __attribute__((always_inline)) {
        short8 ah[2], al[2], bh[4], bl[4];
#pragma unroll
        for (int m = 0; m < 2; ++m) {
            const int arow = wr * 32 + m * 16 + lrow;
            const int aoff = arow * 32 + ((lkg ^ ((arow >> 1) & 3)) << 3);
            ah[m] = *(const short8*)&smem[bufi][0][aoff];
            if constexpr (SPLIT) al[m] = *(const short8*)&smem[bufi][1][aoff];
        }
#pragma unroll
        for (int n = 0; n < 4; ++n) {
            const int brow = wc * 64 + n * 16 + lrow;
            const int boff = brow * 32 + ((lkg ^ ((brow >> 1) & 3)) << 3);
            if constexpr (SPLIT) {
                bh[n] = *(const short8*)&smem[bufi][2][boff];
                bl[n] = *(const short8*)&smem[bufi][3][boff];
            } else {
                bh[n] = *(const short8*)&smem[bufi][1][boff];
            }
        }
        __builtin_amdgcn_s_setprio(1);
#pragma unroll
        for (int m = 0; m < 2; ++m)
#pragma unroll
            for (int n = 0; n < 4; ++n) {
                acc[m][n] = __builtin_amdgcn_mfma_f32_16x16x32_bf16(ah[m], bh[n], acc[m][n], 0, 0, 0);
                if constexpr (SPLIT) {
                    acc[m][n] = __builtin_amdgcn_mfma_f32_16x16x32_bf16(ah[m], bl[n], acc[m][n], 0, 0, 0);
                    acc[m][n] = __builtin_amdgcn_mfma_f32_16x16x32_bf16(al[m], bh[n], acc[m][n], 0, 0, 0);
                }
            }
        __builtin_amdgcn_s_setprio(0);
    };

    STAGE(0, 0);
    STAGE(1, 32);
#pragma unroll 1
    for (int t = 0; t < 32; ++t) {
        __builtin_amdgcn_sched_barrier(0);
        if (t < 30) {
            STAGE((t + 2) & 3, (t + 2) * 32);
            if constexpr (SPLIT) asm volatile("s_waitcnt vmcnt(8)" ::: "memory");
            else                 asm volatile("s_waitcnt vmcnt(4)" ::: "memory");
        } else if (t == 30) {
            if constexpr (SPLIT) asm volatile("s_waitcnt vmcnt(4)" ::: "memory");
            else                 asm volatile("s_waitcnt vmcnt(2)" ::: "memory");
        } else {
            asm volatile("s_waitcnt vmcnt(0)" ::: "memory");
        }
        __builtin_amdgcn_s_barrier();                 // tile t visible to all
        __builtin_amdgcn_sched_barrier(0);
        COMPUTE(t & 3);
        __builtin_amdgcn_sched_barrier(0);
    }

    // epilogue
#pragma unroll
    for (int m = 0; m < 2; ++m)
#pragma unroll
    for (int n = 0; n < 4; ++n) {
        const f32x4 v = acc[m][n];
        ushort hs[4], ls[4];
#pragma unroll
        for (int r = 0; r < 4; ++r) {
            const float x = v[r];
            hs[r] = f2bf(x);
            ls[r] = f2bf(x - bf2f(hs[r]));
        }
        const int row0 = tr + wr * 32 + m * 16 + lkg * 4;
        const int col  = tc + wc * 64 + n * 16 + lrow;
        if (Ch) {
#pragma unroll
            for (int r = 0; r < 4; ++r) {
                const size_t idx = zb + (size_t)(row0 + r) * N + col;
                Ch[idx] = hs[r];
                if (Cl) Cl[idx] = ls[r];
            }
        }
        if (CTh) {
            short4v hv;
            hv[0] = (short)hs[0]; hv[1] = (short)hs[1];
            hv[2] = (short)hs[2]; hv[3] = (short)hs[3];
            *(short4v*)&CTh[zb + (size_t)col * N + row0] = hv;
            if (CTl) {
                short4v lv;
                lv[0] = (short)ls[0]; lv[1] = (short)ls[1];
                lv[2] = (short)ls[2]; lv[3] = (short)ls[3];
                *(short4v*)&CTl[zb + (size_t)col * N + row0] = lv;
            }
        }
    }
}

// ---------------------------------------------------------------------------
// Kernel: gather diag + edges (fallback path only).
// ---------------------------------------------------------------------------
__global__ __launch_bounds__(256) void gather_hl(const ushort* __restrict__ Ph,
                                                 const ushort* __restrict__ Pl,
                                                 const int* __restrict__ eidx,
                                                 float* __restrict__ out,
                                                 int t)
{
    const int tid = blockIdx.x * blockDim.x + threadIdx.x;
    const int ND = S * N;
    if (tid < ND) {
        const int s = tid >> 10;
        const int n = tid & (N - 1);
        const size_t off = ((size_t)s * N + n) * N + n;
        float v = bf2f(Ph[off]);
        if (Pl) v += bf2f(Pl[off]);
        out[(size_t)n * FEAT + s * STEPS + t] = v;
    } else {
        const int idx = tid - ND;
        if (idx >= S * NE) return;
        const int s = idx >> 15;
        const int e = idx & (NE - 1);
        const int i = eidx[e];
        const int j = eidx[NE + e];
        const size_t off = ((size_t)s * N + i) * N + j;
        float v = bf2f(Ph[off]);
        if (Pl) v += bf2f(Pl[off]);
        out[(size_t)N * FEAT + (size_t)e * FEAT + s * STEPS + t] = v;
    }
}

// ---------------------------------------------------------------------------
// Bucketing (counting sort of edges by destination column j = eidx[NE+e]).
// ---------------------------------------------------------------------------
__global__ __launch_bounds__(256) void zero_aux(int* __restrict__ p, int n)
{
    for (int i = blockIdx.x * 256 + threadIdx.x; i < n; i += gridDim.x * 256) p[i] = 0;
}

__global__ __launch_bounds__(256) void edge_hist(const int* __restrict__ eidx,
                                                 int* __restrict__ hist)
{
    const int e = blockIdx.x * 256 + threadIdx.x;
    if (e < NE) atomicAdd(&hist[eidx[NE + e]], 1);
}

__global__ __launch_bounds__(1024) void scan1024(const int* __restrict__ hist,
                                                 int* __restrict__ offs)
{
    __shared__ int tmp[1024];
    const int t = threadIdx.x;
    tmp[t] = hist[t];
    __syncthreads();
    for (int d = 1; d < 1024; d <<= 1) {
        int v = (t >= d) ? tmp[t - d] : 0;
        __syncthreads();
        tmp[t] += v;
        __syncthreads();
    }
    offs[t + 1] = tmp[t];
    if (t == 0) offs[0] = 0;
}

__global__ __launch_bounds__(256) void edge_scatter(const int* __restrict__ eidx,
                                                    const int* __restrict__ offs,
                                                    int* __restrict__ cursor,
                                                    int* __restrict__ perm)
{
    const int e = blockIdx.x * 256 + threadIdx.x;
    if (e < NE) {
        const int j = eidx[NE + e];
        const int pos = atomicAdd(&cursor[j], 1);
        perm[offs[j] + pos] = e;
    }
}

// ---------------------------------------------------------------------------
// Kernel: full-feature extraction (round-10 proven form — 114 us structural
// floor; TA-line-throughput-bound per round-12 K-split experiment).
// Work item = (column j, sigma s) via XCD pair-swizzle (bijective).
// LDS B operand: rows 0..6 = BT_{b=1..7}[j,:], row 7 = BT8[j,:].
//  - k=1..8   : direct LDS reads  bt[b-1][i]
//  - k=9..16  : MFMA acc0 = P8 rows x bt   (n=7 col = k=16)
//  - k=17..24 : MFMA acc1 = P16 rows x bt  (n=7 col = k=24)
//  - k=25..31 : MFMA acc2 = P24 rows x bt  (n=7 discarded)
// C layout: col=lane&15 (=b), row=(lane>>4)*4+r (=task) [m89-verified].
// ---------------------------------------------------------------------------
__global__ __launch_bounds__(256) void extract_k(const ushort* __restrict__ BTe,  // 7 planes
                                                 const ushort* __restrict__ BT8,
                                                 const ushort* __restrict__ A8,
                                                 const ushort* __restrict__ A16,
                                                 const ushort* __restrict__ A24,
                                                 const int* __restrict__ eidx,
                                                 const int* __restrict__ perm,
                                                 const int* __restrict__ offs,
                                                 float* __restrict__ out)
{
    const int id = blockIdx.x;
    const int s  = (id & 7) >> 1;
    const int j  = (id >> 3) * 2 + (id & 1);
    const int tid  = threadIdx.x;
    const int wave = tid >> 6;
    const int lane = tid & 63;

    __shared__ __align__(16) ushort bt[8][1032];
    __shared__ int tlist[MAXT];
    __shared__ int elist[MAXT];

    const int base  = offs[j];
    const int cnt   = min(offs[j + 1] - base, MAXT - 1);
    const int ntask = cnt + 1;                   // + diag task
    const int ngrp  = (ntask + 15) >> 4;

    for (int t0 = tid; t0 < MAXT; t0 += 256) {
        int e = -2, i = j;
        if (t0 < cnt)       { e = perm[base + t0]; i = eidx[e]; }
        else if (t0 == cnt) { e = -1; }
        tlist[t0] = i;
        elist[t0] = e;
    }

    for (int c = tid; c < 8 * 128; c += 256) {
        const int b  = c >> 7;        // 0..7
        const int ch = c & 127;
        const size_t rowoff = ((size_t)s * N + j) * N + ch * 8;
        const short8 v = (b < 7)
            ? *(const short8*)&BTe[(size_t)b * PLANE + rowoff]
            : *(const short8*)&BT8[rowoff];
        *(short8*)&bt[b][ch * 8] = v;
    }
    __syncthreads();

    // ---- k = 1..8 straight from LDS ----
    for (int t0 = tid; t0 < ntask; t0 += 256) {
        const int i = tlist[t0];
        const int e = elist[t0];
        const size_t obase = (e >= 0)
            ? ((size_t)N * FEAT + (size_t)e * FEAT + (size_t)s * STEPS)
            : ((size_t)j * FEAT + (size_t)s * STEPS);
#pragma unroll
        for (int b = 0; b < 8; ++b)
            out[obase + b] = bf2f(bt[b][i]);
    }

    // ---- k = 9..31 via MFMA ----
    const int nidx = lane & 15;
    const ushort* bt_ptr = &bt[nidx < 7 ? nidx : 7][(lane >> 4) * 8];

    for (int g = wave; g < ngrp; g += 4) {
        const int i = tlist[g * 16 + nidx];
        const size_t abase = ((size_t)s * N + i) * N + ((lane >> 4) * 8);
        const ushort* pa0 = A8  + abase;
        const ushort* pa1 = A16 + abase;
        const ushort* pa2 = A24 + abase;

        f32x4 acc0 = {}, acc1 = {}, acc2 = {};
#pragma unroll 4
        for (int ks = 0; ks < 32; ++ks) {
            const short8 bf  = *(const short8*)(bt_ptr + ks * 32);
            const short8 af0 = *(const short8*)(pa0 + ks * 32);
            const short8 af1 = *(const short8*)(pa1 + ks * 32);
            const short8 af2 = *(const short8*)(pa2 + ks * 32);
            acc0 = __builtin_amdgcn_mfma_f32_16x16x32_bf16(af0, bf, acc0, 0, 0, 0);
            acc1 = __builtin_amdgcn_mfma_f32_16x16x32_bf16(af1, bf, acc1, 0, 0, 0);
            acc2 = __builtin_amdgcn_mfma_f32_16x16x32_bf16(af2, bf, acc2, 0, 0, 0);
        }

        if (nidx < 8) {
            const int m0 = (lane >> 4) * 4;
#pragma unroll
            for (int r = 0; r < 4; ++r) {
                const int e = elist[g * 16 + m0 + r];
                if (e >= -1) {
                    const size_t obase = (e >= 0)
                        ? ((size_t)N * FEAT + (size_t)e * FEAT + (size_t)s * STEPS)
                        : ((size_t)j * FEAT + (size_t)s * STEPS);
                    out[obase + 8  + nidx] = acc0[r];          // k = 9..16
                    out[obase + 16 + nidx] = acc1[r];          // k = 17..24
                    if (nidx < 7)
                        out[obase + 24 + nidx] = acc2[r];      // k = 25..31
                }
            }
        }
    }
}

// ---------------------------------------------------------------------------
extern "C" void kernel_launch(void* const* d_in, const int* in_sizes, int n_in,
                              void* d_out, int out_size, void* d_ws, size_t ws_size,
                              hipStream_t stream)
{
    const float* coords     = (const float*)d_in[0];
    const float* log_sigmas = (const float*)d_in[1];
    const int*   eidx       = (const int*)d_in[2];
    float*       out        = (float*)d_out;

    ushort* W = (ushort*)d_ws;
    const dim3 ggrid(N / 128, N / 128, S);
    const dim3 tgrid(16, 16, S);
    ushort* const NUL = nullptr;

    const size_t AUX_INTS = 1024 + 1024 + 1025 + NE;
    const size_t NEED_A   = 15 * PLANE * sizeof(ushort) + AUX_INTS * sizeof(int);

    if (ws_size >= NEED_A) {
        ushort* A0h = W + 0 * PLANE;  ushort* A0l = W + 1 * PLANE;
        ushort* A1h = W + 2 * PLANE;  ushort* A1l = W + 3 * PLANE;
        ushort* A2h = W + 4 * PLANE;
        ushort* BT1l = W + 5 * PLANE;
        ushort* BT8h = W + 6 * PLANE;
        ushort* BT2l = W + 7 * PLANE;           // (plane 7, previously unused)
        ushort* BTe  = W + 8 * PLANE;           // 7 planes: BT1h..BT7h
        int* hist   = (int*)(W + 15 * PLANE);
        int* cursor = hist + 1024;
        int* offs   = cursor + 1024;
        int* perm   = offs + 1025;

        zero_aux<<<8, 256, 0, stream>>>(hist, 2048);   // hist + cursor (contiguous)
        edge_hist<<<NE / 256, 256, 0, stream>>>(eidx, hist);
        scan1024<<<1, 1024, 0, stream>>>(hist, offs);
        edge_scatter<<<NE / 256, 256, 0, stream>>>(eidx, offs, cursor, perm);

        build_P<<<N, 256, 0, stream>>>(coords, log_sigmas, A0h, A0l);
        transpose_hl<<<tgrid, 256, 0, stream>>>(A0h, A0l, BTe + 0 * PLANE, BT1l);

        // Even-power split chain (4 x 3-pass) + odd-power hi-only leaves
        // (1-pass, CT-only).  BT2 (split) is the chain's B operand, produced
        // as fused CTh/CTl of the P2 GEMM.
        ushort* BT1h = BTe + 0 * PLANE;
        ushort* BT2h = BTe + 1 * PLANE;
        // P2 = P1 * P1   (A0 -> A1) + BT2 split
        gemm_tile<true><<<ggrid, 512, 0, stream>>>(A0h, A0l, BT1h, BT1l,
                                                   A1h, A1l, BT2h, BT2l);
        // P3 = P2 * P1   leaf -> BT3h
        gemm_tile<false><<<ggrid, 512, 0, stream>>>(A1h, NUL, BT1h, NUL,
                                                    NUL, NUL, BTe + 2 * PLANE, NUL);
        // P4 = P2 * P2   (A1 -> A0) + BT4h
        gemm_tile<true><<<ggrid, 512, 0, stream>>>(A1h, A1l, BT2h, BT2l,
                                                   A0h, A0l, BTe + 3 * PLANE, NUL);
        // P5 = P4 * P1   leaf -> BT5h
        gemm_tile<false><<<ggrid, 512, 0, stream>>>(A0h, NUL, BT1h, NUL,
                                                    NUL, NUL, BTe + 4 * PLANE, NUL);
        // P6 = P4 * P2   (A0 -> A1) + BT6h
        gemm_tile<true><<<ggrid, 512, 0, stream>>>(A0h, A0l, BT2h, BT2l,
                                                   A1h, A1l, BTe + 5 * PLANE, NUL);
        // P7 = P6 * P1   leaf -> BT7h
        gemm_tile<false><<<ggrid, 512, 0, stream>>>(A1h, NUL, BT1h, NUL,
                                                    NUL, NUL, BTe + 6 * PLANE, NUL);
        // P8 = P6 * P2   (A1 -> A0) + BT8h
        gemm_tile<true><<<ggrid, 512, 0, stream>>>(A1h, A1l, BT2h, BT2l,
                                                   A0h, A0l, BT8h, NUL);
        // P16 = P8 * P8  (hi-only, row-major into A1h)
        gemm_tile<false><<<ggrid, 512, 0, stream>>>(A0h, NUL, BT8h, NUL,
                                                    A1h, NUL, NUL, NUL);
        // P24 = P16 * P8 (hi-only, row-major into A2h)
        gemm_tile<false><<<ggrid, 512, 0, stream>>>(A1h, NUL, BT8h, NUL,
                                                    A2h, NUL, NUL, NUL);

        extract_k<<<N * S, 256, 0, stream>>>(BTe, BT8h, A0h, A1h, A2h,
                                             eidx, perm, offs, out);
    } else {
        // ---- fallback: linear chain (6 planes = 48 MB) ----
        ushort* ping_h = W + 0 * PLANE; ushort* ping_l = W + 1 * PLANE;
        ushort* pong_h = W + 2 * PLANE; ushort* pong_l = W + 3 * PLANE;
        ushort* bt_h   = W + 4 * PLANE; ushort* bt_l   = W + 5 * PLANE;
        const int gather_blocks = (S * N + S * NE + 255) / 256;

        build_P<<<N, 256, 0, stream>>>(coords, log_sigmas, ping_h, ping_l);
        gather_hl<<<gather_blocks, 256, 0, stream>>>(ping_h, ping_l, eidx, out, 0);
        transpose_hl<<<tgrid, 256, 0, stream>>>(ping_h, ping_l, bt_h, bt_l);

        ushort* cur_h = ping_h; ushort* cur_l = ping_l;
        ushort* nxt_h = pong_h; ushort* nxt_l = pong_l;
        for (int k = 2; k <= STEPS; ++k) {
            gemm_tile<true><<<ggrid, 512, 0, stream>>>(cur_h, cur_l, bt_h, bt_l,
                                                       nxt_h, nxt_l, NUL, NUL);
            gather_hl<<<gather_blocks, 256, 0, stream>>>(nxt_h, nxt_l, eidx, out, k - 1);
            ushort* th = cur_h; ushort* tl = cur_l;
            cur_h = nxt_h; cur_l = nxt_l; nxt_h = th; nxt_l = tl;
        }
    }
}

// Round 14
// 352.338 us; speedup vs baseline: 1.1411x; 1.0038x over previous
//
#include <hip/hip_runtime.h>

#define N 1024
#define NE 32768
#define S 4
#define STEPS 31
#define FEAT (S * STEPS)  // 124
#define PLANE ((size_t)S * N * N)   // 4 Mi elements (8 MB as ushort)
#define MAXT 192

typedef short short8 __attribute__((ext_vector_type(8)));
typedef short short4v __attribute__((ext_vector_type(4)));
typedef float f32x4 __attribute__((ext_vector_type(4)));

// ---- bf16 helpers (RNE) ---------------------------------------------------
__device__ __forceinline__ ushort f2bf(float x) {
    union { float f; unsigned u; } v; v.f = x;
    unsigned r = v.u + 0x7fffu + ((v.u >> 16) & 1u);
    return (ushort)(r >> 16);
}
__device__ __forceinline__ float bf2f(ushort h) {
    union { unsigned u; float f; } v; v.u = ((unsigned)h) << 16;
    return v.f;
}

__device__ __forceinline__ void gload16(const ushort* g, ushort* l) {
    __builtin_amdgcn_global_load_lds(
        (const __attribute__((address_space(1))) unsigned int*)g,
        (__attribute__((address_space(3))) unsigned int*)l, 16, 0, 0);
}

// ---------------------------------------------------------------------------
// Kernel: build P (split bf16 hi/lo), row-major [s][i][j].
// ---------------------------------------------------------------------------
__global__ __launch_bounds__(256) void build_P(const float* __restrict__ coords,
                                               const float* __restrict__ log_sigmas,
                                               ushort* __restrict__ Oh,
                                               ushort* __restrict__ Ol)
{
    const int i   = blockIdx.x;
    const int tid = threadIdx.x;

    float sg[S];
#pragma unroll
    for (int s = 0; s < S; ++s) sg[s] = expf(log_sigmas[s]);
#define CSWP(a, b) { float lo = fminf(sg[a], sg[b]); float hi = fmaxf(sg[a], sg[b]); sg[a] = lo; sg[b] = hi; }
    CSWP(0, 1) CSWP(2, 3) CSWP(0, 2) CSWP(1, 3) CSWP(1, 2)
#undef CSWP
    float inv2s2[S];
#pragma unroll
    for (int s = 0; s < S; ++s) inv2s2[s] = 1.0f / (2.0f * sg[s] * sg[s]);

    const float cx = coords[3 * i + 0];
    const float cy = coords[3 * i + 1];
    const float cz = coords[3 * i + 2];

    float w[4][S];
    float part[S] = {0.f, 0.f, 0.f, 0.f};
#pragma unroll
    for (int c = 0; c < 4; ++c) {
        const int j = tid + c * 256;
        const float dx = cx - coords[3 * j + 0];
        const float dy = cy - coords[3 * j + 1];
        const float dz = cz - coords[3 * j + 2];
        const float d2 = dx * dx + dy * dy + dz * dz;
#pragma unroll
        for (int s = 0; s < S; ++s) {
            const float v = (j == i) ? 0.0f : expf(-d2 * inv2s2[s]);
            w[c][s] = v;
            part[s] += v;
        }
    }

    __shared__ float red[S][256];
#pragma unroll
    for (int s = 0; s < S; ++s) red[s][tid] = part[s];
    __syncthreads();
    for (int st = 128; st > 0; st >>= 1) {
        if (tid < st) {
#pragma unroll
            for (int s = 0; s < S; ++s) red[s][tid] += red[s][tid + st];
        }
        __syncthreads();
    }

    float invden[S];
#pragma unroll
    for (int s = 0; s < S; ++s) invden[s] = 1.0f / fmaxf(red[s][0], 1e-12f);

#pragma unroll
    for (int c = 0; c < 4; ++c) {
        const int j = tid + c * 256;
#pragma unroll
        for (int s = 0; s < S; ++s) {
            const float p = w[c][s] * invden[s];
            const size_t off = ((size_t)s * N + i) * N + j;
            const ushort h = f2bf(p);
            Oh[off] = h;
            Ol[off] = f2bf(p - bf2f(h));
        }
    }
}

// ---------------------------------------------------------------------------
// Kernel: transpose hi/lo pair (used once, for BT1).
// ---------------------------------------------------------------------------
__global__ __launch_bounds__(256) void transpose_hl(const ushort* __restrict__ Xh,
                                                    const ushort* __restrict__ Xl,
                                                    ushort* __restrict__ Yh,
                                                    ushort* __restrict__ Yl)
{
    __shared__ float tile[64][65];
    const size_t zb = (size_t)blockIdx.z * N * N;
    const int tr = blockIdx.y * 64, tc = blockIdx.x * 64;
    const int tid = threadIdx.x;
    const int c  = tid & 63;
    const int r0 = tid >> 6;
#pragma unroll
    for (int i = 0; i < 16; ++i) {
        const int r = r0 + i * 4;
        const size_t idx = zb + (size_t)(tr + r) * N + tc + c;
        tile[r][c] = bf2f(Xh[idx]) + bf2f(Xl[idx]);
    }
    __syncthreads();
#pragma unroll
    for (int i = 0; i < 16; ++i) {
        const int r = r0 + i * 4;
        const size_t idx = zb + (size_t)(tc + r) * N + tr + c;
        const float x = tile[c][r];
        const ushort h = f2bf(x);
        Yh[idx] = h;
        if (Yl) Yl[idx] = f2bf(x - bf2f(h));
    }
}

// ---------------------------------------------------------------------------
// Kernel: bf16 MFMA GEMM, 128x128 tile, BK=32, 8 waves, 32x64 wave slice,
// quad-buffered LDS, depth-2 counted-vmcnt prefetch, one barrier per K-step,
// setprio around the MFMA cluster (proven round-10..13 schedule).
// NEW: 1D grid with XCD-pinned row-panels — id&7 = row-panel = XCD (HW
// round-robins linear workgroup id across 8 XCDs), so each XCD's A-panel
// (512KB x 4 sigmas = 2MB hi+lo) stays L2-resident instead of all 8 XCDs
// pulling every A-panel from L3 (split GEMM was L3->L2 BW-bound: 256MB
// per dispatch at ~10.7 TB/s).
// SPLIT=1: C = (Ah+Al)@B, B=(BTh+BTl)^T, 3 MFMA passes.
// SPLIT=0: C = Ah@BTh^T, 1 pass.
// Outputs all nullable: Ch/Cl row-major hi/lo; CTh/CTl transposed hi/lo.
// ---------------------------------------------------------------------------
template <bool SPLIT>
__global__ __launch_bounds__(512) void gemm_tile(const ushort* __restrict__ Ah,
                                                 const ushort* __restrict__ Al,
                                                 const ushort* __restrict__ BTh,
                                                 const ushort* __restrict__ BTl,
                                                 ushort* __restrict__ Ch,
                                                 ushort* __restrict__ Cl,
                                                 ushort* __restrict__ CTh,
                                                 ushort* __restrict__ CTl)
{
    constexpr int NP = SPLIT ? 4 : 2;           // LDS parts
    __shared__ ushort smem[4][NP][128 * 32];    // 128 KB (split) / 64 KB
    const int tid  = threadIdx.x;
    const int w    = tid >> 6;                  // wave 0..7
    const int lane = tid & 63;
    const int wr   = w >> 1;                    // wave row-block 0..3
    const int wc   = w & 1;                     // wave col-block 0..1

    // 1D grid decode: row-panel pinned to XCD (id & 7)
    const int id   = blockIdx.x;                // 0..255
    const int yrow = id & 7;                    // row panel == XCD
    const int rest = id >> 3;
    const int xcol = rest & 7;
    const int z    = rest >> 3;
    const size_t zb = (size_t)z * N * N;
    const int tr = yrow * 128;
    const int tc = xcol * 128;

    const ushort* gA0 = Ah  + zb + (size_t)tr * N;
    const ushort* gA1 = SPLIT ? (Al  + zb + (size_t)tr * N) : nullptr;
    const ushort* gB0 = BTh + zb + (size_t)tc * N;
    const ushort* gB1 = SPLIT ? (BTl + zb + (size_t)tc * N) : nullptr;

    f32x4 acc[2][4] = {};                       // wave's 32x64 slice

    auto STAGE = [&](int bufi, int k0) __attribute__((always_inline)) {
        const int row = tid >> 2;               // 0..127
        const int kg  = (tid & 3) ^ ((row >> 1) & 3);
        const size_t go = (size_t)row * N + k0 + kg * 8;
        const int lb = w * 512;                 // wave-uniform LDS base (elems)
        gload16(gA0 + go, &smem[bufi][0][lb]);
        if constexpr (SPLIT) {
            gload16(gA1 + go, &smem[bufi][1][lb]);
            gload16(gB0 + go, &smem[bufi][2][lb]);
            gload16(gB1 + go, &smem[bufi][3][lb]);
        } else {
            gload16(gB0 + go, &smem[bufi][1][lb]);
        }
    };

    const int lrow = lane & 15;
    const int lkg  = lane >> 4;

    auto COMPUTE = [&](int bufi) __attribute__((always_inline)) {
        short8 ah[2], al[2], bh[4], bl[4];
#pragma unroll
        for (int m = 0; m < 2; ++m) {
            const int arow = wr * 32 + m * 16 + lrow;
            const int aoff = arow * 32 + ((lkg ^ ((arow >> 1) & 3)) << 3);
            ah[m] = *(const short8*)&smem[bufi][0][aoff];
            if constexpr (SPLIT) al[m] = *(const short8*)&smem[bufi][1][aoff];
        }
#pragma unroll
        for (int n = 0; n < 4; ++n) {
            const int brow = wc * 64 + n * 16 + lrow;
            const int boff = brow * 32 + ((lkg ^ ((brow >> 1) & 3)) << 3);
            if constexpr (SPLIT) {
                bh[n] = *(const short8*)&smem[bufi][2][boff];
                bl[n] = *(const short8*)&smem[bufi][3][boff];
            } else {
                bh[n] = *(const short8*)&smem[bufi][1][boff];
            }
        }
        __builtin_amdgcn_s_setprio(1);
#pragma unroll
        for (int m = 0; m < 2; ++m)
#pragma unroll
            for (int n = 0; n < 4; ++n) {
                acc[m][n] = __builtin_amdgcn_mfma_f32_16x16x32_bf16(ah[m], bh[n], acc[m][n], 0, 0, 0);
                if constexpr (SPLIT) {
                    acc[m][n] = __builtin_amdgcn_mfma_f32_16x16x32_bf16(ah[m], bl[n], acc[m][n], 0, 0, 0);
                    acc[m][n] = __builtin_amdgcn_mfma_f32_16x16x32_bf16(al[m], bh[n], acc[m][n], 0, 0, 0);
                }
            }
        __builtin_amdgcn_s_setprio(0);
    };

    STAGE(0, 0);
    STAGE(1, 32);
#pragma unroll 1
    for (int t = 0; t < 32; ++t) {
        __builtin_amdgcn_sched_barrier(0);
        if (t < 30) {
            STAGE((t + 2) & 3, (t + 2) * 32);
            if constexpr (SPLIT) asm volatile("s_waitcnt vmcnt(8)" ::: "memory");
            else                 asm volatile("s_waitcnt vmcnt(4)" ::: "memory");
        } else if (t == 30) {
            if constexpr (SPLIT) asm volatile("s_waitcnt vmcnt(4)" ::: "memory");
            else                 asm volatile("s_waitcnt vmcnt(2)" ::: "memory");
        } else {
            asm volatile("s_waitcnt vmcnt(0)" ::: "memory");
        }
        __builtin_amdgcn_s_barrier();                 // tile t visible to all
        __builtin_amdgcn_sched_barrier(0);
        COMPUTE(t & 3);
        __builtin_amdgcn_sched_barrier(0);
    }

    // epilogue
#pragma unroll
    for (int m = 0; m < 2; ++m)
#pragma unroll
    for (int n = 0; n < 4; ++n) {
        const f32x4 v = acc[m][n];
        ushort hs[4], ls[4];
#pragma unroll
        for (int r = 0; r < 4; ++r) {
            const float x = v[r];
            hs[r] = f2bf(x);
            ls[r] = f2bf(x - bf2f(hs[r]));
        }
        const int row0 = tr + wr * 32 + m * 16 + lkg * 4;
        const int col  = tc + wc * 64 + n * 16 + lrow;
        if (Ch) {
#pragma unroll
            for (int r = 0; r < 4; ++r) {
                const size_t idx = zb + (size_t)(row0 + r) * N + col;
                Ch[idx] = hs[r];
                if (Cl) Cl[idx] = ls[r];
            }
        }
        if (CTh) {
            short4v hv;
            hv[0] = (short)hs[0]; hv[1] = (short)hs[1];
            hv[2] = (short)hs[2]; hv[3] = (short)hs[3];
            *(short4v*)&CTh[zb + (size_t)col * N + row0] = hv;
            if (CTl) {
                short4v lv;
                lv[0] = (short)ls[0]; lv[1] = (short)ls[1];
                lv[2] = (short)ls[2]; lv[3] = (short)ls[3];
                *(short4v*)&CTl[zb + (size_t)col * N + row0] = lv;
            }
        }
    }
}

// ---------------------------------------------------------------------------
// Kernel: gather diag + edges (fallback path only).
// ---------------------------------------------------------------------------
__global__ __launch_bounds__(256) void gather_hl(const ushort* __restrict__ Ph,
                                                 const ushort* __restrict__ Pl,
                                                 const int* __restrict__ eidx,
                                                 float* __restrict__ out,
                                                 int t)
{
    const int tid = blockIdx.x * blockDim.x + threadIdx.x;
    const int ND = S * N;
    if (tid < ND) {
        const int s = tid >> 10;
        const int n = tid & (N - 1);
        const size_t off = ((size_t)s * N + n) * N + n;
        float v = bf2f(Ph[off]);
        if (Pl) v += bf2f(Pl[off]);
        out[(size_t)n * FEAT + s * STEPS + t] = v;
    } else {
        const int idx = tid - ND;
        if (idx >= S * NE) return;
        const int s = idx >> 15;
        const int e = idx & (NE - 1);
        const int i = eidx[e];
        const int j = eidx[NE + e];
        const size_t off = ((size_t)s * N + i) * N + j;
        float v = bf2f(Ph[off]);
        if (Pl) v += bf2f(Pl[off]);
        out[(size_t)N * FEAT + (size_t)e * FEAT + s * STEPS + t] = v;
    }
}

// ---------------------------------------------------------------------------
// Bucketing (counting sort of edges by destination column j = eidx[NE+e]).
// ---------------------------------------------------------------------------
__global__ __launch_bounds__(256) void zero_aux(int* __restrict__ p, int n)
{
    for (int i = blockIdx.x * 256 + threadIdx.x; i < n; i += gridDim.x * 256) p[i] = 0;
}

__global__ __launch_bounds__(256) void edge_hist(const int* __restrict__ eidx,
                                                 int* __restrict__ hist)
{
    const int e = blockIdx.x * 256 + threadIdx.x;
    if (e < NE) atomicAdd(&hist[eidx[NE + e]], 1);
}

__global__ __launch_bounds__(1024) void scan1024(const int* __restrict__ hist,
                                                 int* __restrict__ offs)
{
    __shared__ int tmp[1024];
    const int t = threadIdx.x;
    tmp[t] = hist[t];
    __syncthreads();
    for (int d = 1; d < 1024; d <<= 1) {
        int v = (t >= d) ? tmp[t - d] : 0;
        __syncthreads();
        tmp[t] += v;
        __syncthreads();
    }
    offs[t + 1] = tmp[t];
    if (t == 0) offs[0] = 0;
}

__global__ __launch_bounds__(256) void edge_scatter(const int* __restrict__ eidx,
                                                    const int* __restrict__ offs,
                                                    int* __restrict__ cursor,
                                                    int* __restrict__ perm)
{
    const int e = blockIdx.x * 256 + threadIdx.x;
    if (e < NE) {
        const int j = eidx[NE + e];
        const int pos = atomicAdd(&cursor[j], 1);
        perm[offs[j] + pos] = e;
    }
}

// ---------------------------------------------------------------------------
// Kernel: full-feature extraction (round-10 proven form — 114 us structural
// floor; TA-line-throughput-bound per round-12 K-split experiment).
// Work item = (column j, sigma s) via XCD pair-swizzle (bijective).
// LDS B operand: rows 0..6 = BT_{b=1..7}[j,:], row 7 = BT8[j,:].
//  - k=1..8   : direct LDS reads  bt[b-1][i]
//  - k=9..16  : MFMA acc0 = P8 rows x bt   (n=7 col = k=16)
//  - k=17..24 : MFMA acc1 = P16 rows x bt  (n=7 col = k=24)
//  - k=25..31 : MFMA acc2 = P24 rows x bt  (n=7 discarded)
// C layout: col=lane&15 (=b), row=(lane>>4)*4+r (=task) [m89-verified].
// ---------------------------------------------------------------------------
__global__ __launch_bounds__(256) void extract_k(const ushort* __restrict__ BTe,  // 7 planes
                                                 const ushort* __restrict__ BT8,
                                                 const ushort* __restrict__ A8,
                                                 const ushort* __restrict__ A16,
                                                 const ushort* __restrict__ A24,
                                                 const int* __restrict__ eidx,
                                                 const int* __restrict__ perm,
                                                 const int* __restrict__ offs,
                                                 float* __restrict__ out)
{
    const int id = blockIdx.x;
    const int s  = (id & 7) >> 1;
    const int j  = (id >> 3) * 2 + (id & 1);
    const int tid  = threadIdx.x;
    const int wave = tid >> 6;
    const int lane = tid & 63;

    __shared__ __align__(16) ushort bt[8][1032];
    __shared__ int tlist[MAXT];
    __shared__ int elist[MAXT];

    const int base  = offs[j];
    const int cnt   = min(offs[j + 1] - base, MAXT - 1);
    const int ntask = cnt + 1;                   // + diag task
    const int ngrp  = (ntask + 15) >> 4;

    for (int t0 = tid; t0 < MAXT; t0 += 256) {
        int e = -2, i = j;
        if (t0 < cnt)       { e = perm[base + t0]; i = eidx[e]; }
        else if (t0 == cnt) { e = -1; }
        tlist[t0] = i;
        elist[t0] = e;
    }

    for (int c = tid; c < 8 * 128; c += 256) {
        const int b  = c >> 7;        // 0..7
        const int ch = c & 127;
        const size_t rowoff = ((size_t)s * N + j) * N + ch * 8;
        const short8 v = (b < 7)
            ? *(const short8*)&BTe[(size_t)b * PLANE + rowoff]
            : *(const short8*)&BT8[rowoff];
        *(short8*)&bt[b][ch * 8] = v;
    }
    __syncthreads();

    // ---- k = 1..8 straight from LDS ----
    for (int t0 = tid; t0 < ntask; t0 += 256) {
        const int i = tlist[t0];
        const int e = elist[t0];
        const size_t obase = (e >= 0)
            ? ((size_t)N * FEAT + (size_t)e * FEAT + (size_t)s * STEPS)
            : ((size_t)j * FEAT + (size_t)s * STEPS);
#pragma unroll
        for (int b = 0; b < 8; ++b)
            out[obase + b] = bf2f(bt[b][i]);
    }

    // ---- k = 9..31 via MFMA ----
    const int nidx = lane & 15;
    const ushort* bt_ptr = &bt[nidx < 7 ? nidx : 7][(lane >> 4) * 8];

    for (int g = wave; g < ngrp; g += 4) {
        const int i = tlist[g * 16 + nidx];
        const size_t abase = ((size_t)s * N + i) * N + ((lane >> 4) * 8);
        const ushort* pa0 = A8  + abase;
        const ushort* pa1 = A16 + abase;
        const ushort* pa2 = A24 + abase;

        f32x4 acc0 = {}, acc1 = {}, acc2 = {};
#pragma unroll 4
        for (int ks = 0; ks < 32; ++ks) {
            const short8 bf  = *(const short8*)(bt_ptr + ks * 32);
            const short8 af0 = *(const short8*)(pa0 + ks * 32);
            const short8 af1 = *(const short8*)(pa1 + ks * 32);
            const short8 af2 = *(const short8*)(pa2 + ks * 32);
            acc0 = __builtin_amdgcn_mfma_f32_16x16x32_bf16(af0, bf, acc0, 0, 0, 0);
            acc1 = __builtin_amdgcn_mfma_f32_16x16x32_bf16(af1, bf, acc1, 0, 0, 0);
            acc2 = __builtin_amdgcn_mfma_f32_16x16x32_bf16(af2, bf, acc2, 0, 0, 0);
        }

        if (nidx < 8) {
            const int m0 = (lane >> 4) * 4;
#pragma unroll
            for (int r = 0; r < 4; ++r) {
                const int e = elist[g * 16 + m0 + r];
                if (e >= -1) {
                    const size_t obase = (e >= 0)
                        ? ((size_t)N * FEAT + (size_t)e * FEAT + (size_t)s * STEPS)
                        : ((size_t)j * FEAT + (size_t)s * STEPS);
                    out[obase + 8  + nidx] = acc0[r];          // k = 9..16
                    out[obase + 16 + nidx] = acc1[r];          // k = 17..24
                    if (nidx < 7)
                        out[obase + 24 + nidx] = acc2[r];      // k = 25..31
                }
            }
        }
    }
}

// ---------------------------------------------------------------------------
extern "C" void kernel_launch(void* const* d_in, const int* in_sizes, int n_in,
                              void* d_out, int out_size, void* d_ws, size_t ws_size,
                              hipStream_t stream)
{
    const float* coords     = (const float*)d_in[0];
    const float* log_sigmas = (const float*)d_in[1];
    const int*   eidx       = (const int*)d_in[2];
    float*       out        = (float*)d_out;

    ushort* W = (ushort*)d_ws;
    const int GEMM_BLOCKS = (N / 128) * (N / 128) * S;   // 256, 1D grid
    const dim3 tgrid(16, 16, S);
    ushort* const NUL = nullptr;

    const size_t AUX_INTS = 1024 + 1024 + 1025 + NE;
    const size_t NEED_A   = 15 * PLANE * sizeof(ushort) + AUX_INTS * sizeof(int);

    if (ws_size >= NEED_A) {
        ushort* A0h = W + 0 * PLANE;  ushort* A0l = W + 1 * PLANE;
        ushort* A1h = W + 2 * PLANE;  ushort* A1l = W + 3 * PLANE;
        ushort* A2h = W + 4 * PLANE;
        ushort* BT1l = W + 5 * PLANE;
        ushort* BT8h = W + 6 * PLANE;
        ushort* BT2l = W + 7 * PLANE;
        ushort* BTe  = W + 8 * PLANE;           // 7 planes: BT1h..BT7h
        int* hist   = (int*)(W + 15 * PLANE);
        int* cursor = hist + 1024;
        int* offs   = cursor + 1024;
        int* perm   = offs + 1025;

        zero_aux<<<8, 256, 0, stream>>>(hist, 2048);   // hist + cursor (contiguous)
        edge_hist<<<NE / 256, 256, 0, stream>>>(eidx, hist);
        scan1024<<<1, 1024, 0, stream>>>(hist, offs);
        edge_scatter<<<NE / 256, 256, 0, stream>>>(eidx, offs, cursor, perm);

        build_P<<<N, 256, 0, stream>>>(coords, log_sigmas, A0h, A0l);
        transpose_hl<<<tgrid, 256, 0, stream>>>(A0h, A0l, BTe + 0 * PLANE, BT1l);

        // Even-power split chain (4 x 3-pass) + odd-power hi-only leaves
        // (1-pass, CT-only).  BT2 (split) produced as fused CT of P2 GEMM.
        ushort* BT1h = BTe + 0 * PLANE;
        ushort* BT2h = BTe + 1 * PLANE;
        // P2 = P1 * P1   (A0 -> A1) + BT2 split
        gemm_tile<true><<<GEMM_BLOCKS, 512, 0, stream>>>(A0h, A0l, BT1h, BT1l,
                                                         A1h, A1l, BT2h, BT2l);
        // P3 = P2 * P1   leaf -> BT3h
        gemm_tile<false><<<GEMM_BLOCKS, 512, 0, stream>>>(A1h, NUL, BT1h, NUL,
                                                          NUL, NUL, BTe + 2 * PLANE, NUL);
        // P4 = P2 * P2   (A1 -> A0) + BT4h
        gemm_tile<true><<<GEMM_BLOCKS, 512, 0, stream>>>(A1h, A1l, BT2h, BT2l,
                                                         A0h, A0l, BTe + 3 * PLANE, NUL);
        // P5 = P4 * P1   leaf -> BT5h
        gemm_tile<false><<<GEMM_BLOCKS, 512, 0, stream>>>(A0h, NUL, BT1h, NUL,
                                                          NUL, NUL, BTe + 4 * PLANE, NUL);
        // P6 = P4 * P2   (A0 -> A1) + BT6h
        gemm_tile<true><<<GEMM_BLOCKS, 512, 0, stream>>>(A0h, A0l, BT2h, BT2l,
                                                         A1h, A1l, BTe + 5 * PLANE, NUL);
        // P7 = P6 * P1   leaf -> BT7h
        gemm_tile<false><<<GEMM_BLOCKS, 512, 0, stream>>>(A1h, NUL, BT1h, NUL,
                                                          NUL, NUL, BTe + 6 * PLANE, NUL);
        // P8 = P6 * P2   (A1 -> A0) + BT8h
        gemm_tile<true><<<GEMM_BLOCKS, 512, 0, stream>>>(A1h, A1l, BT2h, BT2l,
                                                         A0h, A0l, BT8h, NUL);
        // P16 = P8 * P8  (hi-only, row-major into A1h)
        gemm_tile<false><<<GEMM_BLOCKS, 512, 0, stream>>>(A0h, NUL, BT8h, NUL,
                                                          A1h, NUL, NUL, NUL);
        // P24 = P16 * P8 (hi-only, row-major into A2h)
        gemm_tile<false><<<GEMM_BLOCKS, 512, 0, stream>>>(A1h, NUL, BT8h, NUL,
                                                          A2h, NUL, NUL, NUL);

        extract_k<<<N * S, 256, 0, stream>>>(BTe, BT8h, A0h, A1h, A2h,
                                             eidx, perm, offs, out);
    } else {
        // ---- fallback: linear chain (6 planes = 48 MB) ----
        ushort* ping_h = W + 0 * PLANE; ushort* ping_l = W + 1 * PLANE;
        ushort* pong_h = W + 2 * PLANE; ushort* pong_l = W + 3 * PLANE;
        ushort* bt_h   = W + 4 * PLANE; ushort* bt_l   = W + 5 * PLANE;
        const int gather_blocks = (S * N + S * NE + 255) / 256;

        build_P<<<N, 256, 0, stream>>>(coords, log_sigmas, ping_h, ping_l);
        gather_hl<<<gather_blocks, 256, 0, stream>>>(ping_h, ping_l, eidx, out, 0);
        transpose_hl<<<tgrid, 256, 0, stream>>>(ping_h, ping_l, bt_h, bt_l);

        ushort* cur_h = ping_h; ushort* cur_l = ping_l;
        ushort* nxt_h = pong_h; ushort* nxt_l = pong_l;
        for (int k = 2; k <= STEPS; ++k) {
            gemm_tile<true><<<GEMM_BLOCKS, 512, 0, stream>>>(cur_h, cur_l, bt_h, bt_l,
                                                             nxt_h, nxt_l, NUL, NUL);
            gather_hl<<<gather_blocks, 256, 0, stream>>>(nxt_h, nxt_l, eidx, out, k - 1);
            ushort* th = cur_h; ushort* tl = cur_l;
            cur_h = nxt_h; cur_l = nxt_l; nxt_h = th; nxt_l = tl;
        }
    }
}